// Round 3
// baseline (439.004 us; speedup 1.0000x reference)
//
#include <hip/hip_runtime.h>
#include <math.h>

// SchroederReverb: 4 series allpass (N=225,556,441,341, g=0.7) then 4 parallel
// feedback combs (N=1116,1188,1277,1356, g=.84,.82,.80,.78) summed.
//
// Lagged recurrence y[n] = a*y[n-N] + u[n] decouples into N*W chains
// (n = k*N + r, column w). Each chain is split into S segments, all resident
// in ONE block: thread (s, w) marches its segment.
//
// Round-3 structure ("march twice", low VGPR):
//   phase 1: segments s>0 march carry-only with assumed y_in=0 (scalar state,
//            no y[] register array); segment 0 marches AND stores (its y_in
//            is genuinely 0). Carries -> LDS, one __syncthreads.
//   fold:    Yin = sum_j a^(L*(s-1-j)) * C[j]   (affine recurrence property)
//   phase 2: s>0 re-march with true incoming state, storing as it goes.
//            Re-reads of `in` hit L2/L3 (segment footprint >> L1 only).
// Comb phase fused: comb1 = plain write; combs 2-4 = ONE kernel, stores via
// contention-free global f32 atomic add (each element gets exactly 3 adds).
//
// Semantics (identical to passing round-2 kernel):
//   allpass: y[k=0]=0; y[k] = (x[k] + g*x[k-1]) + (-g)*y[k-1]  per chain
//   comb:    y[k=0]=0; y[k] =  x[k]             +   g *y[k-1]
//
// Buffers: x -> out(t1) -> ws(t2) -> out(t3) -> ws(t4); comb1: ws -> out
// (write), combs 2-4: ws -> out (atomic add). One 64 MiB scratch.

constexpr int W    = 128;
constexpr int LOGW = 7;
constexpr int MAXS = 16;

// ---- common per-block body -------------------------------------------------
// MODE 0: allpass (write), MODE 1: comb (write), MODE 2: comb (atomic add)
template <int MODE>
__device__ __forceinline__
void stage_body(const float* __restrict__ in, float* __restrict__ out,
                int N, float g, float aL, int L, int T, int bx) {
  const float a = (MODE == 0) ? -g : g;
  __shared__ float C[MAXS][64];

  const int tid = threadIdx.x;
  const int s   = tid >> 6;               // segment index (wave-uniform)
  const int wl  = tid & 63;
  const int r   = bx >> 1;                // chain phase: n = k*N + r
  const int w   = ((bx & 1) << 6) | wl;   // column
  const int stride = N << LOGW;
  const int end    = T << LOGW;
  const int k0     = s * L;
  const int pos0   = ((k0 * N + r) << LOGW) + w;

  if (s == 0) {
    // march + store directly: incoming state is genuinely zero
    float xp = (MODE == 0) ? in[pos0] : 0.f;   // x[k=0], always in range
    float yprev = 0.f;                          // y[k=0] forced to 0
    if (MODE != 2) out[pos0] = 0.f;             // MODE 2 would add 0: skip
    int pos = pos0 + stride;
#pragma unroll 4
    for (int j = 1; j < L; ++j) {
      if (pos < end) {
        float x = in[pos];
        float u = (MODE == 0) ? fmaf(g, xp, x) : x;
        yprev = fmaf(a, yprev, u);
        xp = x;
        if (MODE == 2) unsafeAtomicAdd(&out[pos], yprev);
        else           out[pos] = yprev;
      }
      pos += stride;
    }
    C[0][wl] = yprev;
    __syncthreads();
    return;
  }

  // ---- phase 1: carry-only march with assumed y_in = 0 ----
  {
    float xp = 0.f;
    if (MODE == 0) {
      const int pp = pos0 - stride;            // k0-1 >= 0 always
      xp = (pp < end) ? in[pp] : 0.f;
    }
    float yprev = 0.f;
    int pos = pos0;
#pragma unroll 4
    for (int j = 0; j < L; ++j) {
      float x = (pos < end) ? in[pos] : 0.f;
      float u = (MODE == 0) ? fmaf(g, xp, x) : x;
      yprev = fmaf(a, yprev, u);
      xp = x;
      pos += stride;
    }
    C[s][wl] = yprev;
  }
  __syncthreads();

  // ---- fold incoming state from carries ----
  float Yin = 0.f;                             // true y at k0-1
  for (int j = 0; j < s; ++j) Yin = fmaf(aL, Yin, C[j][wl]);

  // ---- phase 2: re-march with true incoming state, storing ----
  {
    float xp = 0.f;
    if (MODE == 0) {
      const int pp = pos0 - stride;
      xp = (pp < end) ? in[pp] : 0.f;
    }
    float yprev = Yin;
    int pos = pos0;
#pragma unroll 4
    for (int j = 0; j < L; ++j) {
      if (pos < end) {
        float x = in[pos];
        float u = (MODE == 0) ? fmaf(g, xp, x) : x;
        yprev = fmaf(a, yprev, u);
        xp = x;
        if (MODE == 2) unsafeAtomicAdd(&out[pos], yprev);
        else           out[pos] = yprev;
      }
      pos += stride;
    }
  }
}

template <int MODE>
__global__ void stage_k(const float* __restrict__ in, float* __restrict__ out,
                        int N, float g, float aL, int L, int T) {
  stage_body<MODE>(in, out, N, g, aL, L, T, blockIdx.x);
}

// ---- fused combs 2..4 (atomic accumulate), one launch ----------------------
struct CombCfg {
  int   off[4];   // block-range offsets (off[3] = total blocks)
  int   N[3];
  int   L[3];
  float g[3];
  float aL[3];
};

__global__ void comb_fused(const float* __restrict__ in, float* __restrict__ out,
                           CombCfg cfg, int T) {
  int bx = blockIdx.x;
  int i = (bx >= cfg.off[1]) + (bx >= cfg.off[2]);
  stage_body<2>(in, out, cfg.N[i], cfg.g[i], cfg.aL[i], cfg.L[i], T,
                bx - cfg.off[i]);
}

// ---- host ------------------------------------------------------------------
static void pick_SL(int T, int N, int S0, int* Sp, int* Lp) {
  // Kmin = floor(T/N), Kmax = ceil(T/N). Need (S-1)*L <= Kmin so segments
  // 0..S-2 are complete for every chain (only the last segment is ragged,
  // and its carry is never consumed).
  int Kmin = T / N, Kmax = (T + N - 1) / N;
  int S = S0;
  for (; S > 1; --S) {
    int L = (Kmax + S - 1) / S;
    if ((S - 1) * L <= Kmin) break;
  }
  *Sp = S;
  *Lp = (Kmax + S - 1) / S;
}

static float pow_f(float a, int n) {
  double p = 1.0;
  for (int i = 0; i < n; ++i) p *= (double)a;
  return (float)p;
}

extern "C" void kernel_launch(void* const* d_in, const int* in_sizes, int n_in,
                              void* d_out, int out_size, void* d_ws, size_t ws_size,
                              hipStream_t stream) {
  const float* x = (const float*)d_in[0];
  float* out = (float*)d_out;
  float* ws  = (float*)d_ws;              // needs T*W*4 = 64 MiB scratch
  const int T = in_sizes[0] / W;          // 131072

  const int   apN[4] = {225, 556, 441, 341};
  const float gA     = 0.7f;
  const int   cbN[4] = {1116, 1188, 1277, 1356};
  const float cbG[4] = {0.84f, 0.82f, 0.80f, 0.78f};

  // series allpass chain, ping-pong out <-> ws
  const float* src = x;
  float* bufs[2] = {out, ws};
  int cur = 0;
  for (int i = 0; i < 4; ++i) {
    int S, L;
    pick_SL(T, apN[i], (apN[i] < 512) ? 16 : 8, &S, &L);
    float aL = pow_f(-gA, L);
    hipLaunchKernelGGL((stage_k<0>), dim3(apN[i] * 2), dim3(S * 64), 0, stream,
                       src, bufs[cur], apN[i], gA, aL, L, T);
    src = bufs[cur];
    cur ^= 1;
  }
  // src now points at the allpass-chain output (ws for the 4-stage T=131072
  // path); `other` is the remaining buffer, which must be `out`.
  float* dst = (src == out) ? ws : out;   // comb output buffer
  // For the standard path src==ws, dst==out. If T ever makes src==out we
  // still produce the final result in `out` by doing combs into ws then a
  // d2d copy — but with 4 stages cur always ends at src==ws here. Assert-free
  // handling: if dst != out, fall back to comb into dst then async copy.

  // comb 1: plain write
  {
    int S, L;
    pick_SL(T, cbN[0], 4, &S, &L);
    float aL = pow_f(cbG[0], L);
    hipLaunchKernelGGL((stage_k<1>), dim3(cbN[0] * 2), dim3(S * 64), 0, stream,
                       src, dst, cbN[0], cbG[0], aL, L, T);
  }
  // combs 2-4: fused atomic accumulate if all pick S=4, else separate launches
  int S1, L1, S2, L2, S3, L3;
  pick_SL(T, cbN[1], 4, &S1, &L1);
  pick_SL(T, cbN[2], 4, &S2, &L2);
  pick_SL(T, cbN[3], 4, &S3, &L3);
  if (S1 == 4 && S2 == 4 && S3 == 4) {
    CombCfg cfg;
    cfg.off[0] = 0;
    cfg.off[1] = cbN[1] * 2;
    cfg.off[2] = cfg.off[1] + cbN[2] * 2;
    cfg.off[3] = cfg.off[2] + cbN[3] * 2;
    for (int i = 0; i < 3; ++i) {
      cfg.N[i]  = cbN[i + 1];
      cfg.g[i]  = cbG[i + 1];
    }
    cfg.L[0] = L1; cfg.L[1] = L2; cfg.L[2] = L3;
    cfg.aL[0] = pow_f(cbG[1], L1);
    cfg.aL[1] = pow_f(cbG[2], L2);
    cfg.aL[2] = pow_f(cbG[3], L3);
    hipLaunchKernelGGL(comb_fused, dim3(cfg.off[3]), dim3(4 * 64), 0, stream,
                       src, dst, cfg, T);
  } else {
    int Ss[3] = {S1, S2, S3}, Ls[3] = {L1, L2, L3};
    for (int i = 0; i < 3; ++i) {
      float aL = pow_f(cbG[i + 1], Ls[i]);
      hipLaunchKernelGGL((stage_k<2>), dim3(cbN[i + 1] * 2), dim3(Ss[i] * 64),
                         0, stream, src, dst, cbN[i + 1], cbG[i + 1], aL, Ls[i], T);
    }
  }
  if (dst != out) {
    hipMemcpyAsync(out, dst, (size_t)T * W * sizeof(float),
                   hipMemcpyDeviceToDevice, stream);
  }
}

// Round 4
// 354.549 us; speedup vs baseline: 1.2382x; 1.2382x over previous
//
#include <hip/hip_runtime.h>

// SchroederReverb: 4 series allpass (N=225,556,441,341, g=0.7) then 4 parallel
// feedback combs (N=1116,1188,1277,1356, g=.84,.82,.80,.78) summed.
//
// Lagged recurrence y[n] = a*y[n-N] + u[n] decouples into N*W chains
// (n = k*N + r, column w). Chain split into S segments resident in ONE block
// (thread (s, w-pair)); carries via LDS; affine correction:
//   y_true = y_loc + a^(t+1) * Y_in,  Y_in folded from segment carries.
//
// Round-4 structure:
//  - float2 per lane: one wave = one FULL 512 B row (dwordx2, coalesced).
//    Block = S waves (segments) for phase r = blockIdx.x; grid = N.
//  - march-twice (low VGPR ~70): phase 1 carry-only; phase 2 re-march with
//    true incoming state, storing. Re-reads hit L2/L3.
//  - NO atomics (round-3 post-mortem: atomic adds punch through to HBM at
//    2.2 TB/s). Combs: comb1 plain write, combs 2-4 separate RMW passes.
//  - U=8 explicit load batching: 8 independent dwordx2 in flight per lane.
//
// Semantics (identical to passing round-2/3 kernels):
//   allpass: y[k=0]=0; y[k] = (x[k] + g*x[k-1]) + (-g)*y[k-1]   per chain
//   comb:    y[k=0]=0; y[k] =  x[k]             +   g *y[k-1]
//
// Buffers: x -> out(t1) -> ws(t2) -> out(t3) -> ws(t4); comb1: ws -> out
// (write); combs 2-4: ws -> out (read-modify-write). One 64 MiB scratch.

constexpr int W    = 128;   // columns
constexpr int W2   = 64;    // row length in float2
constexpr int MAXS = 16;

// MODE 0: allpass, MODE 1: comb (write), MODE 2: comb (accumulate RMW)
// March `cnt` steps starting at row n (step +N), updating (xp, yp).
// STORE: write y to out (MODE 2: out += y).
template <int MODE, bool STORE>
__device__ __forceinline__
void march(const float2* __restrict__ in, float2* __restrict__ out,
           int n, int N, int cnt, int T, int lane, float g, float a,
           float2& xp, float2& yp) {
  constexpr int U = 8;
  int j = 0;
  while (j + U <= cnt) {
    float2 xs[U];
    float2 os[U];
    int nb = n;
#pragma unroll
    for (int u = 0; u < U; ++u) {
      xs[u] = (nb < T) ? in[nb * W2 + lane] : make_float2(0.f, 0.f);
      nb += N;
    }
    if (MODE == 2 && STORE) {
      nb = n;
#pragma unroll
      for (int u = 0; u < U; ++u) {
        os[u] = (nb < T) ? out[nb * W2 + lane] : make_float2(0.f, 0.f);
        nb += N;
      }
    }
#pragma unroll
    for (int u = 0; u < U; ++u) {
      float2 x = xs[u];
      float ux = (MODE == 0) ? fmaf(g, xp.x, x.x) : x.x;
      float uy = (MODE == 0) ? fmaf(g, xp.y, x.y) : x.y;
      yp.x = fmaf(a, yp.x, ux);
      yp.y = fmaf(a, yp.y, uy);
      xp = x;
      if (STORE && n < T) {
        float2 v = yp;
        if (MODE == 2) { v.x += os[u].x; v.y += os[u].y; }
        out[n * W2 + lane] = v;
      }
      n += N;
    }
    j += U;
  }
  for (; j < cnt; ++j) {
    float2 x = (n < T) ? in[n * W2 + lane] : make_float2(0.f, 0.f);
    float ux = (MODE == 0) ? fmaf(g, xp.x, x.x) : x.x;
    float uy = (MODE == 0) ? fmaf(g, xp.y, x.y) : x.y;
    yp.x = fmaf(a, yp.x, ux);
    yp.y = fmaf(a, yp.y, uy);
    xp = x;
    if (STORE && n < T) {
      float2 v = yp;
      if (MODE == 2) { v.x += out[n * W2 + lane].x, v.y += out[n * W2 + lane].y; }
      out[n * W2 + lane] = v;
    }
    n += N;
  }
}

template <int MODE>
__global__ __launch_bounds__(1024)
void stage2(const float2* __restrict__ in, float2* __restrict__ out,
            int N, float g, float aL, int L, int T) {
  const float a = (MODE == 0) ? -g : g;
  __shared__ float2 C[MAXS][W2];

  const int tid  = threadIdx.x;
  const int s    = tid >> 6;          // segment (wave-uniform)
  const int lane = tid & 63;          // float2 column pair
  const int r    = blockIdx.x;        // chain phase: n = k*N + r
  if (r >= T) return;                 // (tiny-T safety; whole block exits)
  const int k0 = s * L;
  const int n0 = k0 * N + r;

  if (s == 0) {
    // incoming state genuinely zero: march + store in one pass
    float2 xp = make_float2(0.f, 0.f), yp = make_float2(0.f, 0.f);
    if (MODE == 0) xp = in[r * W2 + lane];     // x[k=0]
    if (MODE != 2) out[r * W2 + lane] = make_float2(0.f, 0.f);  // y[k=0] = 0
    march<MODE, true>(in, out, r + N, N, L - 1, T, lane, g, a, xp, yp);
    C[0][lane] = yp;
    __syncthreads();
    return;
  }

  // phase 1: carry-only march with assumed y_in = 0
  {
    float2 xp = make_float2(0.f, 0.f), yp = make_float2(0.f, 0.f);
    if (MODE == 0) xp = in[(n0 - N) * W2 + lane];   // x[k0-1], always in range
    march<MODE, false>(in, out, n0, N, L, T, lane, g, a, xp, yp);
    C[s][lane] = yp;
  }
  __syncthreads();

  // fold incoming state from carries: Y_in = sum_j aL^(s-1-j) * C[j]
  float2 Yin = make_float2(0.f, 0.f);
  for (int j = 0; j < s; ++j) {
    Yin.x = fmaf(aL, Yin.x, C[j][lane].x);
    Yin.y = fmaf(aL, Yin.y, C[j][lane].y);
  }

  // phase 2: re-march with true incoming state, storing
  {
    float2 xp = make_float2(0.f, 0.f), yp = Yin;
    if (MODE == 0) xp = in[(n0 - N) * W2 + lane];
    march<MODE, true>(in, out, n0, N, L, T, lane, g, a, xp, yp);
  }
}

// ---- host ------------------------------------------------------------------
static void pick_SL(int T, int N, int S0, int* Sp, int* Lp) {
  // Need (S-1)*L <= Kmin so segments 0..S-2 are complete for every chain
  // (only the last segment is ragged; its carry is never consumed).
  int Kmin = T / N, Kmax = (T + N - 1) / N;
  int S = S0;
  for (; S > 1; --S) {
    int L = (Kmax + S - 1) / S;
    if ((S - 1) * L <= Kmin) break;
  }
  *Sp = S;
  *Lp = (Kmax + S - 1) / S;
}

static float pow_f(float a, int n) {
  double p = 1.0;
  for (int i = 0; i < n; ++i) p *= (double)a;
  return (float)p;
}

extern "C" void kernel_launch(void* const* d_in, const int* in_sizes, int n_in,
                              void* d_out, int out_size, void* d_ws, size_t ws_size,
                              hipStream_t stream) {
  const float2* x = (const float2*)d_in[0];
  float2* out = (float2*)d_out;
  float2* ws  = (float2*)d_ws;            // needs T*W*4 = 64 MiB scratch
  const int T = in_sizes[0] / W;          // 131072

  const int   apN[4] = {225, 556, 441, 341};
  const float gA     = 0.7f;
  const int   cbN[4] = {1116, 1188, 1277, 1356};
  const float cbG[4] = {0.84f, 0.82f, 0.80f, 0.78f};

  // series allpass chain, ping-pong out <-> ws
  const float2* src = x;
  float2* bufs[2] = {out, ws};
  int cur = 0;
  for (int i = 0; i < 4; ++i) {
    int S, L;
    pick_SL(T, apN[i], MAXS, &S, &L);
    float aL = pow_f(-gA, L);
    hipLaunchKernelGGL((stage2<0>), dim3(apN[i]), dim3(S * 64), 0, stream,
                       src, bufs[cur], apN[i], gA, aL, L, T);
    src = bufs[cur];
    cur ^= 1;
  }
  // with 4 stages src == ws here; comb output goes to `out`
  float2* dst = (src == out) ? ws : out;

  // comb 1: plain write; combs 2-4: RMW accumulate (separate passes, NO atomics)
  for (int i = 0; i < 4; ++i) {
    int S, L;
    pick_SL(T, cbN[i], MAXS, &S, &L);
    float aL = pow_f(cbG[i], L);
    if (i == 0)
      hipLaunchKernelGGL((stage2<1>), dim3(cbN[i]), dim3(S * 64), 0, stream,
                         src, dst, cbN[i], cbG[i], aL, L, T);
    else
      hipLaunchKernelGGL((stage2<2>), dim3(cbN[i]), dim3(S * 64), 0, stream,
                         src, dst, cbN[i], cbG[i], aL, L, T);
  }
  if (dst != out) {
    hipMemcpyAsync(out, dst, (size_t)T * W * sizeof(float),
                   hipMemcpyDeviceToDevice, stream);
  }
}

// Round 5
// 292.040 us; speedup vs baseline: 1.5032x; 1.2140x over previous
//
#include <hip/hip_runtime.h>

// SchroederReverb: 4 series allpass (N=225,556,441,341, g=0.7) then 4 parallel
// feedback combs (N=1116,1188,1277,1356, g=.84,.82,.80,.78) summed.
//
// Lagged recurrence y[n] = a*y[n-N] + u[n] decouples into N*W chains
// (n = k*N + r, column w). Chain split into S segments resident in ONE block;
// thread (segment s, lane) marches its segment ONCE keeping locals y[0..L)
// in registers (L is compile-time), exchanges carries through LDS, then the
// store pass applies the affine correction y_true[j] = y[j] + a^(j+1)*Yin.
//
// Round-5: march-ONCE (round-4's march-twice re-read cost 64MB/stage of
// logical traffic; reverted). V=2 (float2, full 512B row per wave) for all
// stages except N=225 which uses V=1 half-rows so grid=450 covers all CUs.
// Segments 0..S-2 are provably in-bounds ((S-1)*L <= Kmin) -> unpredicated
// hot loops; only wave s=S-1 runs the predicated variant. NO atomics
// (round-3: atomic adds ran at 2.2 TB/s). Combs: comb1 write, combs 2-4 RMW.
//
// Semantics (identical to passing rounds 1-4):
//   allpass: y[k=0]=0; y[k] = (x[k] + g*x[k-1]) + (-g)*y[k-1]   per chain
//   comb:    y[k=0]=0; y[k] =  x[k]             +   g *y[k-1]
//
// Buffers: x -> out -> ws -> out -> ws; combs: ws -> out. 64 MiB scratch.

constexpr int W = 128;

template <int V> struct fv { float d[V]; };

template <int V>
__device__ __forceinline__ fv<V> fv_zero() {
  fv<V> r;
#pragma unroll
  for (int c = 0; c < V; ++c) r.d[c] = 0.f;
  return r;
}

// ---- march a block of K steps (registers carried through xp, yp) ----------
template <int MODE, int K, bool PRED, int V>
__device__ __forceinline__
void march_blk(const fv<V>* __restrict__ in, int idx, int stepIdx, int endIdx,
               float g, float a, fv<V>& xp, fv<V>& yp, fv<V>* __restrict__ y) {
  fv<V> xs[K];
#pragma unroll
  for (int u = 0; u < K; ++u) {
    int id = idx + u * stepIdx;
    xs[u] = (!PRED || id < endIdx) ? in[id] : fv_zero<V>();
  }
#pragma unroll
  for (int u = 0; u < K; ++u) {
#pragma unroll
    for (int c = 0; c < V; ++c) {
      float x = xs[u].d[c];
      float uu = (MODE == 0) ? fmaf(g, xp.d[c], x) : x;
      yp.d[c] = fmaf(a, yp.d[c], uu);
    }
    xp = xs[u];
    y[u] = yp;
  }
}

template <int MODE, int CNT, bool PRED, int V>
__device__ __forceinline__
void march_seg(const fv<V>* __restrict__ in, int idx, int stepIdx, int endIdx,
               float g, float a, fv<V>& xp, fv<V>& yp, fv<V>* __restrict__ y) {
  constexpr int U = 8;
  constexpr int NB = CNT / U, R = CNT % U;
#pragma unroll
  for (int b = 0; b < NB; ++b)
    march_blk<MODE, U, PRED, V>(in, idx + b * U * stepIdx, stepIdx, endIdx,
                                g, a, xp, yp, y + b * U);
  if constexpr (R > 0)
    march_blk<MODE, R, PRED, V>(in, idx + NB * U * stepIdx, stepIdx, endIdx,
                                g, a, xp, yp, y + NB * U);
}

// ---- store pass: y_true[j] = y[j] + a^(j+1)*Yin (MODE 2: += out) ----------
template <int MODE, int K, bool PRED, int V>
__device__ __forceinline__
void store_blk(fv<V>* __restrict__ out, int idx, int stepIdx, int endIdx,
               float a, fv<V> Yin, const fv<V>* __restrict__ y, float& p) {
  fv<V> os[K];
  if constexpr (MODE == 2) {
#pragma unroll
    for (int u = 0; u < K; ++u) {
      int id = idx + u * stepIdx;
      os[u] = (!PRED || id < endIdx) ? out[id] : fv_zero<V>();
    }
  }
#pragma unroll
  for (int u = 0; u < K; ++u) {
    int id = idx + u * stepIdx;
    fv<V> v;
#pragma unroll
    for (int c = 0; c < V; ++c) {
      v.d[c] = fmaf(p, Yin.d[c], y[u].d[c]);
      if (MODE == 2) v.d[c] += os[u].d[c];
    }
    if (!PRED || id < endIdx) out[id] = v;
    p *= a;
  }
}

template <int MODE, int CNT, bool PRED, int V>
__device__ __forceinline__
void store_seg(fv<V>* __restrict__ out, int idx, int stepIdx, int endIdx,
               float a, fv<V> Yin, const fv<V>* __restrict__ y, float p0) {
  constexpr int U = 8;
  constexpr int NB = CNT / U, R = CNT % U;
  float p = p0;
#pragma unroll
  for (int b = 0; b < NB; ++b)
    store_blk<MODE, U, PRED, V>(out, idx + b * U * stepIdx, stepIdx, endIdx,
                                a, Yin, y + b * U, p);
  if constexpr (R > 0)
    store_blk<MODE, R, PRED, V>(out, idx + NB * U * stepIdx, stepIdx, endIdx,
                                a, Yin, y + NB * U, p);
}

// ---- one stage, compile-time config ---------------------------------------
// grid = (N, W/(64*V)); block = S waves. Wave s marches segment s of chain
// (r = blockIdx.x) over 64*V consecutive columns.
template <int MODE, int S, int L, int V>
__global__ __launch_bounds__(S * 64)
void stage_ro(const fv<V>* __restrict__ in, fv<V>* __restrict__ out,
              int N, float g, float aL, int T) {
  const float a = (MODE == 0) ? -g : g;
  constexpr int RW = W / V;                 // row width in fv<V> units
  __shared__ fv<V> C[S][64];

  const int tid  = threadIdx.x;
  const int s    = tid >> 6;                // segment (wave-uniform)
  const int lane = (tid & 63) + blockIdx.y * 64;
  const int r    = blockIdx.x;              // chain phase: n = k*N + r
  const int stepIdx = N * RW;
  const int endIdx  = T * RW;
  const int idx0 = (s * L * N + r) * RW + lane;

  fv<V> y[L];
  fv<V> xp = fv_zero<V>();
  fv<V> yp = fv_zero<V>();

  if (s == 0) {
    if (MODE == 0) xp = in[r * RW + lane];          // x[k=0]
    y[0] = fv_zero<V>();                            // y[k=0] forced to 0
    march_seg<MODE, L - 1, false, V>(in, idx0 + stepIdx, stepIdx, endIdx,
                                     g, a, xp, yp, y + 1);
  } else {
    if (MODE == 0) xp = in[idx0 - stepIdx];         // x[k0-1], always in range
    if (s < S - 1)
      march_seg<MODE, L, false, V>(in, idx0, stepIdx, endIdx, g, a, xp, yp, y);
    else
      march_seg<MODE, L, true,  V>(in, idx0, stepIdx, endIdx, g, a, xp, yp, y);
  }
  C[s][tid & 63] = yp;
  __syncthreads();

  // fold incoming state: Yin = sum_{j<s} aL^(s-1-j) * C[j]
  fv<V> Yin = fv_zero<V>();
  for (int j = 0; j < s; ++j) {
#pragma unroll
    for (int c = 0; c < V; ++c)
      Yin.d[c] = fmaf(aL, Yin.d[c], C[j][tid & 63].d[c]);
  }

  if (s < S - 1)
    store_seg<MODE, L, false, V>(out, idx0, stepIdx, endIdx, a, Yin, y, a);
  else
    store_seg<MODE, L, true,  V>(out, idx0, stepIdx, endIdx, a, Yin, y, a);
}

// ---- generic fallback (any T): round-4 march-twice kernel ------------------
constexpr int W2 = 64;
template <int MODE, bool STORE>
__device__ __forceinline__
void g_march(const float2* __restrict__ in, float2* __restrict__ out,
             int n, int N, int cnt, int T, int lane, float g, float a,
             float2& xp, float2& yp) {
  for (int j = 0; j < cnt; ++j) {
    float2 x = (n < T) ? in[n * W2 + lane] : make_float2(0.f, 0.f);
    float ux = (MODE == 0) ? fmaf(g, xp.x, x.x) : x.x;
    float uy = (MODE == 0) ? fmaf(g, xp.y, x.y) : x.y;
    yp.x = fmaf(a, yp.x, ux);
    yp.y = fmaf(a, yp.y, uy);
    xp = x;
    if (STORE && n < T) {
      float2 v = yp;
      if (MODE == 2) { v.x += out[n * W2 + lane].x; v.y += out[n * W2 + lane].y; }
      out[n * W2 + lane] = v;
    }
    n += N;
  }
}

template <int MODE>
__global__ __launch_bounds__(1024)
void stage_gen(const float2* __restrict__ in, float2* __restrict__ out,
               int N, float g, float aL, int L, int T) {
  const float a = (MODE == 0) ? -g : g;
  __shared__ float2 C[16][W2];
  const int tid = threadIdx.x, s = tid >> 6, lane = tid & 63;
  const int r = blockIdx.x;
  if (r >= T) return;
  const int n0 = s * L * N + r;
  if (s == 0) {
    float2 xp = make_float2(0.f, 0.f), yp = make_float2(0.f, 0.f);
    if (MODE == 0) xp = in[r * W2 + lane];
    if (MODE != 2) out[r * W2 + lane] = make_float2(0.f, 0.f);
    g_march<MODE, true>(in, out, r + N, N, L - 1, T, lane, g, a, xp, yp);
    C[0][lane] = yp;
    __syncthreads();
    return;
  }
  {
    float2 xp = make_float2(0.f, 0.f), yp = make_float2(0.f, 0.f);
    if (MODE == 0) xp = in[(n0 - N) * W2 + lane];
    g_march<MODE, false>(in, out, n0, N, L, T, lane, g, a, xp, yp);
    C[s][lane] = yp;
  }
  __syncthreads();
  float2 Yin = make_float2(0.f, 0.f);
  for (int j = 0; j < s; ++j) {
    Yin.x = fmaf(aL, Yin.x, C[j][lane].x);
    Yin.y = fmaf(aL, Yin.y, C[j][lane].y);
  }
  float2 xp = make_float2(0.f, 0.f), yp = Yin;
  if (MODE == 0) xp = in[(n0 - N) * W2 + lane];
  g_march<MODE, true>(in, out, n0, N, L, T, lane, g, a, xp, yp);
}

// ---- host ------------------------------------------------------------------
static void pick_SL(int T, int N, int S0, int* Sp, int* Lp) {
  int Kmin = T / N, Kmax = (T + N - 1) / N;
  int S = S0;
  for (; S > 1; --S) {
    int L = (Kmax + S - 1) / S;
    if ((S - 1) * L <= Kmin) break;
  }
  *Sp = S;
  *Lp = (Kmax + *Sp - 1) / *Sp;
}

static float pow_f(float a, int n) {
  double p = 1.0;
  for (int i = 0; i < n; ++i) p *= (double)a;
  return (float)p;
}

extern "C" void kernel_launch(void* const* d_in, const int* in_sizes, int n_in,
                              void* d_out, int out_size, void* d_ws, size_t ws_size,
                              hipStream_t stream) {
  float* out = (float*)d_out;
  float* ws  = (float*)d_ws;              // needs T*W*4 = 64 MiB scratch
  const float* x = (const float*)d_in[0];
  const int T = in_sizes[0] / W;          // 131072

  if (T == 131072) {
    // Verified: S*L >= Kmax (coverage) and (S-1)*L <= Kmin (only the last
    // segment ragged) for every stage at T=131072.
    const fv<1>* x1 = (const fv<1>*)x;
    fv<1>* o1 = (fv<1>*)out;
    const fv<2>* o2c = (const fv<2>*)out;
    fv<2>* o2 = (fv<2>*)out;
    const fv<2>* w2c = (const fv<2>*)ws;
    fv<2>* w2 = (fv<2>*)ws;

    // AP1 N=225 (K=583): V=1, grid 225x2, S=16, L=37
    hipLaunchKernelGGL((stage_ro<0, 16, 37, 1>), dim3(225, 2), dim3(1024), 0,
                       stream, x1, o1, 225, 0.7f, pow_f(-0.7f, 37), T);
    // AP2 N=556 (K=236): S=16, L=15
    hipLaunchKernelGGL((stage_ro<0, 16, 15, 2>), dim3(556, 1), dim3(1024), 0,
                       stream, o2c, w2, 556, 0.7f, pow_f(-0.7f, 15), T);
    // AP3 N=441 (K=298): S=16, L=19
    hipLaunchKernelGGL((stage_ro<0, 16, 19, 2>), dim3(441, 1), dim3(1024), 0,
                       stream, w2c, o2, 441, 0.7f, pow_f(-0.7f, 19), T);
    // AP4 N=341 (K=385): S=16, L=25
    hipLaunchKernelGGL((stage_ro<0, 16, 25, 2>), dim3(341, 1), dim3(1024), 0,
                       stream, o2c, w2, 341, 0.7f, pow_f(-0.7f, 25), T);
    // comb1 N=1116 (K=118): S=15, L=8  (write)
    hipLaunchKernelGGL((stage_ro<1, 15, 8, 2>), dim3(1116, 1), dim3(960), 0,
                       stream, w2c, o2, 1116, 0.84f, pow_f(0.84f, 8), T);
    // comb2 N=1188 (K=111): S=16, L=7  (RMW)
    hipLaunchKernelGGL((stage_ro<2, 16, 7, 2>), dim3(1188, 1), dim3(1024), 0,
                       stream, w2c, o2, 1188, 0.82f, pow_f(0.82f, 7), T);
    // comb3 N=1277 (K=103): S=15, L=7  (RMW)
    hipLaunchKernelGGL((stage_ro<2, 15, 7, 2>), dim3(1277, 1), dim3(960), 0,
                       stream, w2c, o2, 1277, 0.80f, pow_f(0.80f, 7), T);
    // comb4 N=1356 (K=97): S=14, L=7  (RMW)
    hipLaunchKernelGGL((stage_ro<2, 14, 7, 2>), dim3(1356, 1), dim3(896), 0,
                       stream, w2c, o2, 1356, 0.78f, pow_f(0.78f, 7), T);
  } else {
    const int   apN[4] = {225, 556, 441, 341};
    const int   cbN[4] = {1116, 1188, 1277, 1356};
    const float cbG[4] = {0.84f, 0.82f, 0.80f, 0.78f};
    const float2* src = (const float2*)x;
    float2* bufs[2] = {(float2*)out, (float2*)ws};
    int cur = 0;
    for (int i = 0; i < 4; ++i) {
      int S, L;
      pick_SL(T, apN[i], 16, &S, &L);
      hipLaunchKernelGGL((stage_gen<0>), dim3(apN[i]), dim3(S * 64), 0, stream,
                         src, bufs[cur], apN[i], 0.7f, pow_f(-0.7f, L), L, T);
      src = bufs[cur];
      cur ^= 1;
    }
    float2* dst = (src == (float2*)out) ? (float2*)ws : (float2*)out;
    for (int i = 0; i < 4; ++i) {
      int S, L;
      pick_SL(T, cbN[i], 16, &S, &L);
      if (i == 0)
        hipLaunchKernelGGL((stage_gen<1>), dim3(cbN[i]), dim3(S * 64), 0, stream,
                           src, dst, cbN[i], cbG[i], pow_f(cbG[i], L), L, T);
      else
        hipLaunchKernelGGL((stage_gen<2>), dim3(cbN[i]), dim3(S * 64), 0, stream,
                           src, dst, cbN[i], cbG[i], pow_f(cbG[i], L), L, T);
    }
    if (dst != (float2*)out)
      hipMemcpyAsync(out, dst, (size_t)T * W * sizeof(float),
                     hipMemcpyDeviceToDevice, stream);
  }
}

// Round 6
// 285.856 us; speedup vs baseline: 1.5358x; 1.0216x over previous
//
#include <hip/hip_runtime.h>

// SchroederReverb: 4 series allpass (N=225,556,441,341, g=0.7) then 4 parallel
// feedback combs (N=1116,1188,1277,1356, g=.84,.82,.80,.78) summed.
//
// Lagged recurrence y[n] = a*y[n-N] + u[n] decouples into N*W chains
// (n = k*N + r, column w). Chain split into S segments resident in ONE block;
// thread (segment s, lane) marches its segment ONCE keeping locals y[0..L)
// in registers, exchanges carries through LDS, then the store pass applies
// the affine correction y_true[j] = y[j] + a^(j+1)*Yin.
//
// Round-6: widen per-wave footprint.
//   V=2: float2/lane, wave = 1 full 512B row.
//   V=4: float4/lane, wave = 2 consecutive rows (2 chains, 1 KiB granule,
//        4 independent FMA chains per lane). Odd-N handled by per-lane
//        chain-valid guard (endIdx=0 => loads give 0, stores skipped).
// AP1 V=2 (S=16,L=37); AP2/AP3 V=4; AP4 V=2 (VGPR-bound); combs V=4.
// NO atomics (round-3: 2.2 TB/s). Combs: comb1 write, combs 2-4 RMW.
//
// Semantics (identical to passing rounds 1-5):
//   allpass: y[k=0]=0; y[k] = (x[k] + g*x[k-1]) + (-g)*y[k-1]   per chain
//   comb:    y[k=0]=0; y[k] =  x[k]             +   g *y[k-1]
//
// Buffers: x -> out -> ws -> out -> ws; combs: ws -> out. 64 MiB scratch.

constexpr int W = 128;

template <int V> struct fv { float d[V]; };

template <int V>
__device__ __forceinline__ fv<V> fv_zero() {
  fv<V> r;
#pragma unroll
  for (int c = 0; c < V; ++c) r.d[c] = 0.f;
  return r;
}

// ---- march a block of K steps (state carried through xp, yp) ---------------
template <int MODE, int K, bool PRED, int V>
__device__ __forceinline__
void march_blk(const fv<V>* __restrict__ in, int idx, int stepIdx, int endIdx,
               float g, float a, fv<V>& xp, fv<V>& yp, fv<V>* __restrict__ y) {
  fv<V> xs[K];
#pragma unroll
  for (int u = 0; u < K; ++u) {
    int id = idx + u * stepIdx;
    xs[u] = (!PRED || id < endIdx) ? in[id] : fv_zero<V>();
  }
#pragma unroll
  for (int u = 0; u < K; ++u) {
#pragma unroll
    for (int c = 0; c < V; ++c) {
      float x = xs[u].d[c];
      float uu = (MODE == 0) ? fmaf(g, xp.d[c], x) : x;
      yp.d[c] = fmaf(a, yp.d[c], uu);
    }
    xp = xs[u];
    y[u] = yp;
  }
}

template <int MODE, int CNT, bool PRED, int V, int U = 8>
__device__ __forceinline__
void march_seg(const fv<V>* __restrict__ in, int idx, int stepIdx, int endIdx,
               float g, float a, fv<V>& xp, fv<V>& yp, fv<V>* __restrict__ y) {
  constexpr int NB = CNT / U, R = CNT % U;
#pragma unroll
  for (int b = 0; b < NB; ++b)
    march_blk<MODE, U, PRED, V>(in, idx + b * U * stepIdx, stepIdx, endIdx,
                                g, a, xp, yp, y + b * U);
  if constexpr (R > 0)
    march_blk<MODE, R, PRED, V>(in, idx + NB * U * stepIdx, stepIdx, endIdx,
                                g, a, xp, yp, y + NB * U);
}

// ---- store pass: y_true[j] = y[j] + a^(j+1)*Yin (MODE 2: += out) ----------
template <int MODE, int K, bool PRED, int V>
__device__ __forceinline__
void store_blk(fv<V>* __restrict__ out, int idx, int stepIdx, int endIdx,
               float a, fv<V> Yin, const fv<V>* __restrict__ y, float& p) {
  fv<V> os[K];
  if constexpr (MODE == 2) {
#pragma unroll
    for (int u = 0; u < K; ++u) {
      int id = idx + u * stepIdx;
      os[u] = (!PRED || id < endIdx) ? out[id] : fv_zero<V>();
    }
  }
#pragma unroll
  for (int u = 0; u < K; ++u) {
    int id = idx + u * stepIdx;
    fv<V> v;
#pragma unroll
    for (int c = 0; c < V; ++c) {
      v.d[c] = fmaf(p, Yin.d[c], y[u].d[c]);
      if (MODE == 2) v.d[c] += os[u].d[c];
    }
    if (!PRED || id < endIdx) out[id] = v;
    p *= a;
  }
}

template <int MODE, int CNT, bool PRED, int V, int U = 8>
__device__ __forceinline__
void store_seg(fv<V>* __restrict__ out, int idx, int stepIdx, int endIdx,
               float a, fv<V> Yin, const fv<V>* __restrict__ y, float p0) {
  constexpr int NB = CNT / U, R = CNT % U;
  float p = p0;
#pragma unroll
  for (int b = 0; b < NB; ++b)
    store_blk<MODE, U, PRED, V>(out, idx + b * U * stepIdx, stepIdx, endIdx,
                                a, Yin, y + b * U, p);
  if constexpr (R > 0)
    store_blk<MODE, R, PRED, V>(out, idx + NB * U * stepIdx, stepIdx, endIdx,
                                a, Yin, y + NB * U, p);
}

// ---- one stage -------------------------------------------------------------
// V<=2: wave = one row (or half-row via blockIdx.y for V=1), grid.x = N.
// V==4: wave = 2 consecutive rows (chains 2bx, 2bx+1), grid.x = ceil(N/2).
//       ODDN: per-lane chain-valid guard via endIdx=0.
template <int MODE, int S, int L, int V, bool ODDN, int U = 8>
__global__ __launch_bounds__(S * 64)
void stage_ro(const fv<V>* __restrict__ in, fv<V>* __restrict__ out,
              int N, float g, float aL, int T) {
  const float a = (MODE == 0) ? -g : g;
  constexpr int RW = W / V;                 // row width in fv<V> units
  __shared__ fv<V> C[S][64];

  const int tid = threadIdx.x;
  const int s   = tid >> 6;                 // segment (wave-uniform)
  const int l6  = tid & 63;

  int r, laneoff;
  bool valid = true;
  if constexpr (V == 4) {
    r = (blockIdx.x << 1) | (l6 >> 5);      // 2 chains per wave
    laneoff = l6 & 31;
    if constexpr (ODDN) valid = (r < N);
  } else {
    r = blockIdx.x;
    laneoff = l6 + blockIdx.y * 64;
  }
  const int stepIdx = N * RW;
  const int endIdx  = valid ? T * RW : 0;
  const int idx0    = (s * L * N + r) * RW + laneoff;

  fv<V> y[L];
  fv<V> xp = fv_zero<V>();
  fv<V> yp = fv_zero<V>();

  if (s == 0) {
    if (MODE == 0) xp = in[r * RW + laneoff];     // x[k=0]; addr safe even if !valid
    y[0] = fv_zero<V>();                          // y[k=0] forced to 0
    march_seg<MODE, L - 1, ODDN, V, U>(in, idx0 + stepIdx, stepIdx, endIdx,
                                       g, a, xp, yp, y + 1);
  } else {
    if (MODE == 0) xp = in[idx0 - stepIdx];       // x[k0-1]; addr safe
    if (!ODDN && s < S - 1)
      march_seg<MODE, L, false, V, U>(in, idx0, stepIdx, endIdx, g, a, xp, yp, y);
    else
      march_seg<MODE, L, true,  V, U>(in, idx0, stepIdx, endIdx, g, a, xp, yp, y);
  }
  C[s][l6] = yp;
  __syncthreads();

  // fold incoming state: Yin = sum_{j<s} aL^(s-1-j) * C[j]
  fv<V> Yin = fv_zero<V>();
  for (int j = 0; j < s; ++j) {
#pragma unroll
    for (int c = 0; c < V; ++c)
      Yin.d[c] = fmaf(aL, Yin.d[c], C[j][l6].d[c]);
  }

  if (!ODDN && s < S - 1)
    store_seg<MODE, L, false, V, U>(out, idx0, stepIdx, endIdx, a, Yin, y, a);
  else
    store_seg<MODE, L, true,  V, U>(out, idx0, stepIdx, endIdx, a, Yin, y, a);
}

// ---- generic fallback (any T): march-twice float2 kernel -------------------
constexpr int W2 = 64;
template <int MODE, bool STORE>
__device__ __forceinline__
void g_march(const float2* __restrict__ in, float2* __restrict__ out,
             int n, int N, int cnt, int T, int lane, float g, float a,
             float2& xp, float2& yp) {
  for (int j = 0; j < cnt; ++j) {
    float2 x = (n < T) ? in[n * W2 + lane] : make_float2(0.f, 0.f);
    float ux = (MODE == 0) ? fmaf(g, xp.x, x.x) : x.x;
    float uy = (MODE == 0) ? fmaf(g, xp.y, x.y) : x.y;
    yp.x = fmaf(a, yp.x, ux);
    yp.y = fmaf(a, yp.y, uy);
    xp = x;
    if (STORE && n < T) {
      float2 v = yp;
      if (MODE == 2) { v.x += out[n * W2 + lane].x; v.y += out[n * W2 + lane].y; }
      out[n * W2 + lane] = v;
    }
    n += N;
  }
}

template <int MODE>
__global__ __launch_bounds__(1024)
void stage_gen(const float2* __restrict__ in, float2* __restrict__ out,
               int N, float g, float aL, int L, int T) {
  const float a = (MODE == 0) ? -g : g;
  __shared__ float2 C[16][W2];
  const int tid = threadIdx.x, s = tid >> 6, lane = tid & 63;
  const int r = blockIdx.x;
  if (r >= T) return;
  const int n0 = s * L * N + r;
  if (s == 0) {
    float2 xp = make_float2(0.f, 0.f), yp = make_float2(0.f, 0.f);
    if (MODE == 0) xp = in[r * W2 + lane];
    if (MODE != 2) out[r * W2 + lane] = make_float2(0.f, 0.f);
    g_march<MODE, true>(in, out, r + N, N, L - 1, T, lane, g, a, xp, yp);
    C[0][lane] = yp;
    __syncthreads();
    return;
  }
  {
    float2 xp = make_float2(0.f, 0.f), yp = make_float2(0.f, 0.f);
    if (MODE == 0) xp = in[(n0 - N) * W2 + lane];
    g_march<MODE, false>(in, out, n0, N, L, T, lane, g, a, xp, yp);
    C[s][lane] = yp;
  }
  __syncthreads();
  float2 Yin = make_float2(0.f, 0.f);
  for (int j = 0; j < s; ++j) {
    Yin.x = fmaf(aL, Yin.x, C[j][lane].x);
    Yin.y = fmaf(aL, Yin.y, C[j][lane].y);
  }
  float2 xp = make_float2(0.f, 0.f), yp = Yin;
  if (MODE == 0) xp = in[(n0 - N) * W2 + lane];
  g_march<MODE, true>(in, out, n0, N, L, T, lane, g, a, xp, yp);
}

// ---- host ------------------------------------------------------------------
static void pick_SL(int T, int N, int S0, int* Sp, int* Lp) {
  int Kmin = T / N, Kmax = (T + N - 1) / N;
  int S = S0;
  for (; S > 1; --S) {
    int L = (Kmax + S - 1) / S;
    if ((S - 1) * L <= Kmin) break;
  }
  *Sp = S;
  *Lp = (Kmax + *Sp - 1) / *Sp;
}

static float pow_f(float a, int n) {
  double p = 1.0;
  for (int i = 0; i < n; ++i) p *= (double)a;
  return (float)p;
}

extern "C" void kernel_launch(void* const* d_in, const int* in_sizes, int n_in,
                              void* d_out, int out_size, void* d_ws, size_t ws_size,
                              hipStream_t stream) {
  float* out = (float*)d_out;
  float* ws  = (float*)d_ws;              // needs T*W*4 = 64 MiB scratch
  const float* x = (const float*)d_in[0];
  const int T = in_sizes[0] / W;          // 131072

  if (T == 131072) {
    // Per stage: S*L >= Kmax (coverage), (S-1)*L <= Kmin (only tail ragged).
    const fv<2>* x2  = (const fv<2>*)x;
    fv<2>* o2 = (fv<2>*)out;  const fv<2>* o2c = (const fv<2>*)out;
    fv<2>* w2 = (fv<2>*)ws;   const fv<2>* w2c = (const fv<2>*)ws;
    fv<4>* o4 = (fv<4>*)out;  const fv<4>* o4c = (const fv<4>*)out;
    fv<4>* w4 = (fv<4>*)ws;   const fv<4>* w4c = (const fv<4>*)ws;

    // AP1 N=225 (K=583): V=2, S=16, L=37  [~110 VGPR]
    hipLaunchKernelGGL((stage_ro<0, 16, 37, 2, false>), dim3(225), dim3(1024),
                       0, stream, x2, o2, 225, 0.7f, pow_f(-0.7f, 37), T);
    // AP2 N=556 (K=236): V=4, S=16, L=15, grid=278
    hipLaunchKernelGGL((stage_ro<0, 16, 15, 4, false>), dim3(278), dim3(1024),
                       0, stream, o4c, w4, 556, 0.7f, pow_f(-0.7f, 15), T);
    // AP3 N=441 odd (K=298): V=4, S=16, L=19, grid=221, U=4 (VGPR cap)
    hipLaunchKernelGGL((stage_ro<0, 16, 19, 4, true, 4>), dim3(221), dim3(1024),
                       0, stream, w4c, o4, 441, 0.7f, pow_f(-0.7f, 19), T);
    // AP4 N=341 (K=385): V=2, S=16, L=25
    hipLaunchKernelGGL((stage_ro<0, 16, 25, 2, false>), dim3(341), dim3(1024),
                       0, stream, o2c, w2, 341, 0.7f, pow_f(-0.7f, 25), T);
    // comb1 N=1116 (K=118): V=4, S=15, L=8, grid=558 (write)
    hipLaunchKernelGGL((stage_ro<1, 15, 8, 4, false>), dim3(558), dim3(960),
                       0, stream, w4c, o4, 1116, 0.84f, pow_f(0.84f, 8), T);
    // comb2 N=1188 (K=111): V=4, S=16, L=7, grid=594 (RMW)
    hipLaunchKernelGGL((stage_ro<2, 16, 7, 4, false>), dim3(594), dim3(1024),
                       0, stream, w4c, o4, 1188, 0.82f, pow_f(0.82f, 7), T);
    // comb3 N=1277 odd (K=103): V=4, S=15, L=7, grid=639 (RMW)
    hipLaunchKernelGGL((stage_ro<2, 15, 7, 4, true>), dim3(639), dim3(960),
                       0, stream, w4c, o4, 1277, 0.80f, pow_f(0.80f, 7), T);
    // comb4 N=1356 (K=97): V=4, S=14, L=7, grid=678 (RMW)
    hipLaunchKernelGGL((stage_ro<2, 14, 7, 4, false>), dim3(678), dim3(896),
                       0, stream, w4c, o4, 1356, 0.78f, pow_f(0.78f, 7), T);
  } else {
    const int   apN[4] = {225, 556, 441, 341};
    const int   cbN[4] = {1116, 1188, 1277, 1356};
    const float cbG[4] = {0.84f, 0.82f, 0.80f, 0.78f};
    const float2* src = (const float2*)x;
    float2* bufs[2] = {(float2*)out, (float2*)ws};
    int cur = 0;
    for (int i = 0; i < 4; ++i) {
      int S, L;
      pick_SL(T, apN[i], 16, &S, &L);
      hipLaunchKernelGGL((stage_gen<0>), dim3(apN[i]), dim3(S * 64), 0, stream,
                         src, bufs[cur], apN[i], 0.7f, pow_f(-0.7f, L), L, T);
      src = bufs[cur];
      cur ^= 1;
    }
    float2* dst = (src == (float2*)out) ? (float2*)ws : (float2*)out;
    for (int i = 0; i < 4; ++i) {
      int S, L;
      pick_SL(T, cbN[i], 16, &S, &L);
      if (i == 0)
        hipLaunchKernelGGL((stage_gen<1>), dim3(cbN[i]), dim3(S * 64), 0, stream,
                           src, dst, cbN[i], cbG[i], pow_f(cbG[i], L), L, T);
      else
        hipLaunchKernelGGL((stage_gen<2>), dim3(cbN[i]), dim3(S * 64), 0, stream,
                           src, dst, cbN[i], cbG[i], pow_f(cbG[i], L), L, T);
    }
    if (dst != (float2*)out)
      hipMemcpyAsync(out, dst, (size_t)T * W * sizeof(float),
                     hipMemcpyDeviceToDevice, stream);
  }
}